// Round 6
// baseline (1433.756 us; speedup 1.0000x reference)
//
#include <hip/hip_runtime.h>

#define NC 300000
#define NP 150000
#define NG 2000
#define NB 500
#define SCAN_B 1024   // block scans 2048 elements
#define NR 8          // bin8 key ranges (one per XCD via blockIdx%8)

typedef unsigned int u32;

static inline unsigned cdiv(long long a, long long b) { return (unsigned)((a + b - 1) / b); }

// ---------- bf16 helpers ----------
__device__ __forceinline__ float b2f(u32 h) {
    union { u32 u; float f; } c; c.u = h << 16; return c.f;
}
__device__ __forceinline__ u32 f2b(float f) {
    union { float f; u32 u; } c; c.f = f;
    return (c.u + 0x7FFFu + ((c.u >> 16) & 1u)) >> 16;   // RNE
}
__device__ __forceinline__ void unpack8(uint4 v, float* o) {
    o[0] = b2f(v.x & 0xFFFFu); o[1] = b2f(v.x >> 16);
    o[2] = b2f(v.y & 0xFFFFu); o[3] = b2f(v.y >> 16);
    o[4] = b2f(v.z & 0xFFFFu); o[5] = b2f(v.z >> 16);
    o[6] = b2f(v.w & 0xFFFFu); o[7] = b2f(v.w >> 16);
}
__device__ __forceinline__ uint4 pack8(const float* a) {
    uint4 v;
    v.x = f2b(a[0]) | (f2b(a[1]) << 16);
    v.y = f2b(a[2]) | (f2b(a[3]) << 16);
    v.z = f2b(a[4]) | (f2b(a[5]) << 16);
    v.w = f2b(a[6]) | (f2b(a[7]) << 16);
    return v;
}

// ---------- fused f32->bf16 convert of all 4 tables (+ f32 copy for g/b outputs) ----------
__global__ void convert_all(const float* __restrict__ cw, const float* __restrict__ pw,
                            const float* __restrict__ gw, const float* __restrict__ bw,
                            uint4* __restrict__ c16, uint4* __restrict__ p16,
                            uint4* __restrict__ g16, uint4* __restrict__ b16,
                            float* __restrict__ outg, float* __restrict__ outb) {
    const int C8 = NC * 8, P8 = NP * 8, G8 = NG * 8, B8 = NB * 8;
    int i = blockIdx.x * blockDim.x + threadIdx.x;
    const float* in; uint4* out16; float* cpy = nullptr; int j;
    if (i < C8)                         { in = cw; out16 = c16; j = i; }
    else if ((j = i - C8) < P8)         { in = pw; out16 = p16; }
    else if ((j = i - C8 - P8) < G8)    { in = gw; out16 = g16; cpy = outg; }
    else if ((j = i - C8 - P8 - G8) < B8){ in = bw; out16 = b16; cpy = outb; }
    else return;
    const float4* p = (const float4*)(in + (size_t)j * 8);
    float4 a = p[0], b = p[1];
    float t[8] = { a.x, a.y, a.z, a.w, b.x, b.y, b.z, b.w };
    out16[j] = pack8(t);
    if (cpy) { float4* q = (float4*)(cpy + (size_t)j * 8); q[0] = a; q[1] = b; }
}

// ---------- fused CSR build over all 6 edge sets ----------
struct Edges6 {
    const int* src[6];
    const int* dst[6];
    int cum[7];      // cumulative edge-count offsets (cum[6] = total)
    int ctbase[7];   // base key of each set's count segment (ctbase[6] = RTOT)
};

__global__ void count6(Edges6 e, int* __restrict__ ct, int total) {
    int id = blockIdx.x * blockDim.x + threadIdx.x;
    if (id >= total) return;
    int k = 0;
    #pragma unroll
    for (int q = 1; q < 6; ++q) k += (id >= e.cum[q]);
    int j = id - e.cum[k];
    atomicAdd(ct + e.ctbase[k] + e.src[k][j], 1);
}

// ---------- global exclusive scan, 2048 elems/block ----------
__global__ void scan1(const int* __restrict__ in, int* __restrict__ out,
                      int* __restrict__ bsum, int n) {
    __shared__ int sm[SCAN_B];
    int t = threadIdx.x;
    int i0 = blockIdx.x * 2048 + 2 * t, i1 = i0 + 1;
    int v0 = (i0 < n) ? in[i0] : 0;
    int v1 = (i1 < n) ? in[i1] : 0;
    int pair = v0 + v1;
    sm[t] = pair; __syncthreads();
    for (int off = 1; off < SCAN_B; off <<= 1) {
        int add = (t >= off) ? sm[t - off] : 0;
        __syncthreads();
        sm[t] += add; __syncthreads();
    }
    int excl = sm[t] - pair;
    if (i0 < n) out[i0] = excl;
    if (i1 < n) out[i1] = excl + v0;
    if (t == SCAN_B - 1) bsum[blockIdx.x] = sm[t];
}
__global__ void scan2(int* __restrict__ bsum, int nb) {
    __shared__ int sm[SCAN_B];
    int t = threadIdx.x;
    int v = (t < nb) ? bsum[t] : 0;
    sm[t] = v; __syncthreads();
    for (int off = 1; off < SCAN_B; off <<= 1) {
        int add = (t >= off) ? sm[t - off] : 0;
        __syncthreads();
        sm[t] += add; __syncthreads();
    }
    if (t < nb) bsum[t] = sm[t] - v;
}
// adds block offsets into rp; also emits per-bucket staging tails (rp at key%128==0)
__global__ void scan3(int* __restrict__ rp, int* __restrict__ btail,
                      const int* __restrict__ bsum, int n) {
    int b = bsum[blockIdx.x];
    #pragma unroll
    for (int k = 0; k < 2; ++k) {
        int idx = blockIdx.x * 2048 + k * SCAN_B + threadIdx.x;
        if (idx < n) {
            int v = rp[idx] + b;
            rp[idx] = v;
            if ((idx & 127) == 0) btail[idx >> 7] = v;
        }
    }
}

// ---------- pass 1: bin edges into 8204 coarse buckets (bucket = key>>7) ----------
// stage word = (key&127)<<19 | dst   (dst < 2^19 = 524288 > NC)
// blockIdx%NR partitions the key space -> each bucket tail written by one XCD;
// nontemporal edge reads keep the tail lines resident in L2.
__global__ void bin8(Edges6 e, int* __restrict__ btail, u32* __restrict__ stage,
                     int k1, int groupThreads) {
    int r = blockIdx.x & (NR - 1);
    int lo = r * k1, hi = lo + k1;
    int t0 = (blockIdx.x >> 3) * blockDim.x + threadIdx.x;
    #pragma unroll
    for (int k = 0; k < 6; ++k) {
        int kb = e.ctbase[k], ke = e.ctbase[k + 1];
        if (ke <= lo || kb >= hi) continue;        // set doesn't overlap range
        int nk = e.cum[k + 1] - e.cum[k];
        const int* __restrict__ srk = e.src[k];
        const int* __restrict__ dsk = e.dst[k];
        for (int j = t0; j < nk; j += groupThreads) {
            int key = kb + __builtin_nontemporal_load(srk + j);
            if (key >= lo && key < hi) {
                int d = __builtin_nontemporal_load(dsk + j);
                int p = atomicAdd(btail + (key >> 7), 1);
                stage[p] = ((u32)(key & 127) << 19) | (u32)d;
            }
        }
    }
}

// ---------- pass 2: one block per bucket, LDS counting-place -> dense pm ----------
__global__ void sort_bucket(const int* __restrict__ rp, const u32* __restrict__ stage,
                            int* __restrict__ pm, int rtot, int tot) {
    __shared__ int cur[128];
    int b = blockIdx.x;
    int k0 = b << 7;
    int base = rp[k0];
    int t = threadIdx.x;
    if (t < 128) {
        int ki = k0 + t;
        cur[t] = (ki < rtot) ? (rp[ki] - base) : 0;
    }
    __syncthreads();
    int end = (k0 + 128 < rtot) ? rp[k0 + 128] : tot;
    int nE = end - base;
    for (int i = t; i < nE; i += blockDim.x) {
        u32 w = stage[base + i];
        int klow = w >> 19;
        int d = (int)(w & 0x7FFFFu);
        int off = atomicAdd(&cur[klow], 1);
        pm[base + off] = d;
    }
}

// ---------- mean-agg of bf16 rows, f32 accumulate, 4-deep MLP ----------
__device__ __forceinline__ void acc8(uint4 v, float* sum) {
    float t[8]; unpack8(v, t);
    #pragma unroll
    for (int k = 0; k < 8; ++k) sum[k] += t[k];
}
__device__ __forceinline__ void agg8(const int* __restrict__ rp, const int* __restrict__ pm,
                                     const uint4* __restrict__ tgt,
                                     int row, int lane, float w, float* acc) {
    int s = rp[row], e = rp[row + 1];
    float sum[8] = {0, 0, 0, 0, 0, 0, 0, 0};
    int i = s;
    for (; i + 4 <= e; i += 4) {
        int d0 = pm[i], d1 = pm[i + 1], d2 = pm[i + 2], d3 = pm[i + 3];
        uint4 v0 = tgt[(size_t)d0 * 8 + lane];
        uint4 v1 = tgt[(size_t)d1 * 8 + lane];
        uint4 v2 = tgt[(size_t)d2 * 8 + lane];
        uint4 v3 = tgt[(size_t)d3 * 8 + lane];
        acc8(v0, sum); acc8(v1, sum); acc8(v2, sum); acc8(v3, sum);
    }
    for (; i < e; ++i) {
        uint4 v = tgt[(size_t)pm[i] * 8 + lane];
        acc8(v, sum);
    }
    int deg = e - s;
    float sc = w / (float)(deg > 1 ? deg : 1);
    #pragma unroll
    for (int k = 0; k < 8; ++k) acc[k] += sum[k] * sc;
}

// ---------- fused layer ----------
// mode 0 = seed out, 1 = out += acc, 2 = out = (out+acc)*0.25 and skip next write
__global__ void layer_kernel(
    const int* __restrict__ rp_purch, const int* __restrict__ rp_pby,
    const int* __restrict__ rp_sim,   const int* __restrict__ rp_cop,
    const int* __restrict__ rp_bel,   const int* __restrict__ rp_comp,
    const int* __restrict__ pm,
    const uint4* __restrict__ c16, const uint4* __restrict__ p16,
    const uint4* __restrict__ g16, const uint4* __restrict__ b16,
    uint4* __restrict__ c16n, uint4* __restrict__ p16n,
    float* __restrict__ outc, float* __restrict__ outp,
    int mode)
{
    int t = blockIdx.x * blockDim.x + threadIdx.x;
    int gid = t >> 3;
    int lane = t & 7;
    float acc[8];
    if (gid < NP) {
        int row = gid;
        size_t idx = (size_t)row * 8 + lane;
        float base[8]; unpack8(p16[idx], base);
        #pragma unroll
        for (int k = 0; k < 8; ++k) acc[k] = base[k];
        agg8(rp_pby,  pm, c16, row, lane, 1.0f, acc);
        agg8(rp_sim,  pm, p16, row, lane, 0.5f, acc);
        agg8(rp_cop,  pm, p16, row, lane, 0.3f, acc);
        agg8(rp_bel,  pm, g16, row, lane, 0.2f, acc);
        agg8(rp_comp, pm, b16, row, lane, 0.2f, acc);
        if (mode != 2) p16n[idx] = pack8(acc);
        float4* o = (float4*)(outp + (size_t)row * 64 + lane * 8);
        float4 o0, o1;
        if (mode == 0) {
            o0 = make_float4(base[0], base[1], base[2], base[3]);
            o1 = make_float4(base[4], base[5], base[6], base[7]);
        } else { o0 = o[0]; o1 = o[1]; }
        o0.x += acc[0]; o0.y += acc[1]; o0.z += acc[2]; o0.w += acc[3];
        o1.x += acc[4]; o1.y += acc[5]; o1.z += acc[6]; o1.w += acc[7];
        if (mode == 2) {
            o0.x *= 0.25f; o0.y *= 0.25f; o0.z *= 0.25f; o0.w *= 0.25f;
            o1.x *= 0.25f; o1.y *= 0.25f; o1.z *= 0.25f; o1.w *= 0.25f;
        }
        o[0] = o0; o[1] = o1;
    } else if (gid < NP + NC) {
        int row = gid - NP;
        size_t idx = (size_t)row * 8 + lane;
        #pragma unroll
        for (int k = 0; k < 8; ++k) acc[k] = 0.f;
        agg8(rp_purch, pm, p16, row, lane, 1.0f, acc);
        if (mode != 2) c16n[idx] = pack8(acc);
        float4* o = (float4*)(outc + (size_t)row * 64 + lane * 8);
        float4 o0, o1;
        if (mode == 0) {
            float base[8]; unpack8(c16[idx], base);
            o0 = make_float4(base[0], base[1], base[2], base[3]);
            o1 = make_float4(base[4], base[5], base[6], base[7]);
        } else { o0 = o[0]; o1 = o[1]; }
        o0.x += acc[0]; o0.y += acc[1]; o0.z += acc[2]; o0.w += acc[3];
        o1.x += acc[4]; o1.y += acc[5]; o1.z += acc[6]; o1.w += acc[7];
        if (mode == 2) {
            o0.x *= 0.25f; o0.y *= 0.25f; o0.z *= 0.25f; o0.w *= 0.25f;
            o1.x *= 0.25f; o1.y *= 0.25f; o1.z *= 0.25f; o1.w *= 0.25f;
        }
        o[0] = o0; o[1] = o1;
    }
}

extern "C" void kernel_launch(void* const* d_in, const int* in_sizes, int n_in,
                              void* d_out, int out_size, void* d_ws, size_t ws_size,
                              hipStream_t stream) {
    const float* cust_w  = (const float*)d_in[0];
    const float* prod_w  = (const float*)d_in[1];
    const float* group_w = (const float*)d_in[2];
    const float* brand_w = (const float*)d_in[3];

    const int n_purch = in_sizes[4];
    const int n_pby   = in_sizes[6];
    const int n_sim   = in_sizes[8];
    const int n_cop   = in_sizes[10];
    const int n_bel   = in_sizes[12];
    const int n_comp  = in_sizes[14];
    const int n_edges[6] = { n_purch, n_pby, n_sim, n_cop, n_bel, n_comp };

    const size_t CSZ = (size_t)NC * 64;
    const size_t PSZ = (size_t)NP * 64;

    // ---- workspace layout ----
    char* base = (char*)d_ws;
    uint4* c16A = (uint4*)base;                 base += (size_t)NC * 128;
    uint4* c16B = (uint4*)base;                 base += (size_t)NC * 128;
    uint4* p16A = (uint4*)base;                 base += (size_t)NP * 128;
    uint4* p16B = (uint4*)base;                 base += (size_t)NP * 128;
    uint4* g16  = (uint4*)base;                 base += (size_t)NG * 128;
    uint4* b16  = (uint4*)base;                 base += (size_t)NB * 128;

    const int RP_PURCH = NC + 1;
    const int RP_OTHER = NP + 1;
    const int RTOT = RP_PURCH + 5 * RP_OTHER;   // 1,050,006
    const int NBKT = cdiv(RTOT, 128);           // 8204 coarse buckets

    int* rp_all = (int*)base;                   base += (size_t)RTOT * 4;
    int* ct_all = (int*)base;                   base += (size_t)RTOT * 4;
    long long tot_edges = 0;
    for (int k = 0; k < 6; ++k) tot_edges += n_edges[k];
    int* pm_all = (int*)base;                   base += tot_edges * 4;
    u32* stage  = (u32*)base;                   base += tot_edges * 4;
    int* btail  = (int*)base;                   base += (size_t)NBKT * 4;
    int* bsum   = (int*)base;

    int* rp_purch = rp_all;
    int* rp_pby   = rp_purch + RP_PURCH;
    int* rp_sim   = rp_pby + RP_OTHER;
    int* rp_cop   = rp_sim + RP_OTHER;
    int* rp_bel   = rp_cop + RP_OTHER;
    int* rp_comp  = rp_bel + RP_OTHER;

    float* out_c = (float*)d_out;
    float* out_p = out_c + CSZ;
    float* out_g = out_p + PSZ;
    float* out_b = out_g + (size_t)NG * 64;

    const int BT = 256;

    // ---- fused convert (also copies group/brand f32 outputs) ----
    const long long CVT = (long long)(NC + NP + NG + NB) * 8;
    convert_all<<<cdiv(CVT, BT), BT, 0, stream>>>(
        cust_w, prod_w, group_w, brand_w, c16A, p16A, g16, b16, out_g, out_b);

    // ---- fused CSR build: count -> scan -> bin -> bucket-sort ----
    Edges6 E;
    E.src[0] = (const int*)d_in[4];  E.dst[0] = (const int*)d_in[5];
    E.src[1] = (const int*)d_in[6];  E.dst[1] = (const int*)d_in[7];
    E.src[2] = (const int*)d_in[8];  E.dst[2] = (const int*)d_in[9];
    E.src[3] = (const int*)d_in[10]; E.dst[3] = (const int*)d_in[11];
    E.src[4] = (const int*)d_in[12]; E.dst[4] = (const int*)d_in[13];
    E.src[5] = (const int*)d_in[14]; E.dst[5] = (const int*)d_in[15];
    E.cum[0] = 0;
    for (int k = 0; k < 6; ++k) E.cum[k + 1] = E.cum[k] + n_edges[k];
    E.ctbase[0] = 0;
    E.ctbase[1] = RP_PURCH;
    for (int k = 2; k < 6; ++k) E.ctbase[k] = E.ctbase[k - 1] + RP_OTHER;
    E.ctbase[6] = RTOT;
    const int TOT = E.cum[6];

    hipMemsetAsync(ct_all, 0, (size_t)RTOT * 4, stream);
    count6<<<cdiv(TOT, BT), BT, 0, stream>>>(E, ct_all, TOT);
    {
        int nb = cdiv(RTOT, 2048);   // 513
        scan1<<<nb, SCAN_B, 0, stream>>>(ct_all, rp_all, bsum, RTOT);
        scan2<<<1, SCAN_B, 0, stream>>>(bsum, nb);
        scan3<<<nb, SCAN_B, 0, stream>>>(rp_all, btail, bsum, RTOT);
    }
    {
        const int K1 = cdiv(NBKT, NR) * 128;     // key range per XCD, bucket-aligned
        const int GRP = 512;                     // blocks per range-group
        const int groupThreads = GRP * BT;
        bin8<<<NR * GRP, BT, 0, stream>>>(E, btail, stage, K1, groupThreads);
    }
    sort_bucket<<<NBKT, BT, 0, stream>>>(rp_all, stage, pm_all, RTOT, TOT);

    // ---- 3 fused layers ----
    const long long LTHREADS = (long long)(NP + NC) * 8;
    layer_kernel<<<cdiv(LTHREADS, BT), BT, 0, stream>>>(
        rp_purch, rp_pby, rp_sim, rp_cop, rp_bel, rp_comp, pm_all,
        c16A, p16A, g16, b16, c16B, p16B, out_c, out_p, 0);
    layer_kernel<<<cdiv(LTHREADS, BT), BT, 0, stream>>>(
        rp_purch, rp_pby, rp_sim, rp_cop, rp_bel, rp_comp, pm_all,
        c16B, p16B, g16, b16, c16A, p16A, out_c, out_p, 1);
    layer_kernel<<<cdiv(LTHREADS, BT), BT, 0, stream>>>(
        rp_purch, rp_pby, rp_sim, rp_cop, rp_bel, rp_comp, pm_all,
        c16A, p16A, g16, b16, c16B, p16B, out_c, out_p, 2);
}

// Round 7
// 1119.555 us; speedup vs baseline: 1.2806x; 1.2806x over previous
//
#include <hip/hip_runtime.h>

#define NC 300000
#define NP 150000
#define NG 2000
#define NB 500
#define SCAN_B 1024   // block scans 2048 elements
#define NR 8          // placement key ranges (one per XCD via blockIdx%8)

typedef unsigned int u32;

static inline unsigned cdiv(long long a, long long b) { return (unsigned)((a + b - 1) / b); }

// ---------- bf16 helpers ----------
__device__ __forceinline__ float b2f(u32 h) {
    union { u32 u; float f; } c; c.u = h << 16; return c.f;
}
__device__ __forceinline__ u32 f2b(float f) {
    union { float f; u32 u; } c; c.f = f;
    return (c.u + 0x7FFFu + ((c.u >> 16) & 1u)) >> 16;   // RNE
}
__device__ __forceinline__ void unpack8(uint4 v, float* o) {
    o[0] = b2f(v.x & 0xFFFFu); o[1] = b2f(v.x >> 16);
    o[2] = b2f(v.y & 0xFFFFu); o[3] = b2f(v.y >> 16);
    o[4] = b2f(v.z & 0xFFFFu); o[5] = b2f(v.z >> 16);
    o[6] = b2f(v.w & 0xFFFFu); o[7] = b2f(v.w >> 16);
}
__device__ __forceinline__ uint4 pack8(const float* a) {
    uint4 v;
    v.x = f2b(a[0]) | (f2b(a[1]) << 16);
    v.y = f2b(a[2]) | (f2b(a[3]) << 16);
    v.z = f2b(a[4]) | (f2b(a[5]) << 16);
    v.w = f2b(a[6]) | (f2b(a[7]) << 16);
    return v;
}

// ---------- fused f32->bf16 convert of all 4 tables (+ f32 copy for g/b outputs) ----------
__global__ void convert_all(const float* __restrict__ cw, const float* __restrict__ pw,
                            const float* __restrict__ gw, const float* __restrict__ bw,
                            uint4* __restrict__ c16, uint4* __restrict__ p16,
                            uint4* __restrict__ g16, uint4* __restrict__ b16,
                            float* __restrict__ outg, float* __restrict__ outb) {
    const int C8 = NC * 8, P8 = NP * 8, G8 = NG * 8, B8 = NB * 8;
    int i = blockIdx.x * blockDim.x + threadIdx.x;
    const float* in; uint4* out16; float* cpy = nullptr; int j;
    if (i < C8)                         { in = cw; out16 = c16; j = i; }
    else if ((j = i - C8) < P8)         { in = pw; out16 = p16; }
    else if ((j = i - C8 - P8) < G8)    { in = gw; out16 = g16; cpy = outg; }
    else if ((j = i - C8 - P8 - G8) < B8){ in = bw; out16 = b16; cpy = outb; }
    else return;
    const float4* p = (const float4*)(in + (size_t)j * 8);
    float4 a = p[0], b = p[1];
    float t[8] = { a.x, a.y, a.z, a.w, b.x, b.y, b.z, b.w };
    out16[j] = pack8(t);
    if (cpy) { float4* q = (float4*)(cpy + (size_t)j * 8); q[0] = a; q[1] = b; }
}

// ---------- fused CSR build over all 6 edge sets ----------
struct Edges6 {
    const int* src[6];
    const int* dst[6];
    int cum[7];      // cumulative edge-count offsets (cum[6] = total)
    int ctbase[7];   // base key of each set's count segment (ctbase[6] = RTOT)
};

__global__ void count6(Edges6 e, int* __restrict__ ct, int total) {
    int id = blockIdx.x * blockDim.x + threadIdx.x;
    if (id >= total) return;
    int k = 0;
    #pragma unroll
    for (int q = 1; q < 6; ++q) k += (id >= e.cum[q]);
    int j = id - e.cum[k];
    atomicAdd(ct + e.ctbase[k] + e.src[k][j], 1);
}

// ---------- global exclusive scan, 2048 elems/block ----------
__global__ void scan1(const int* __restrict__ in, int* __restrict__ out,
                      int* __restrict__ bsum, int n) {
    __shared__ int sm[SCAN_B];
    int t = threadIdx.x;
    int i0 = blockIdx.x * 2048 + 2 * t, i1 = i0 + 1;
    int v0 = (i0 < n) ? in[i0] : 0;
    int v1 = (i1 < n) ? in[i1] : 0;
    int pair = v0 + v1;
    sm[t] = pair; __syncthreads();
    for (int off = 1; off < SCAN_B; off <<= 1) {
        int add = (t >= off) ? sm[t - off] : 0;
        __syncthreads();
        sm[t] += add; __syncthreads();
    }
    int excl = sm[t] - pair;
    if (i0 < n) out[i0] = excl;
    if (i1 < n) out[i1] = excl + v0;
    if (t == SCAN_B - 1) bsum[blockIdx.x] = sm[t];
}
__global__ void scan2(int* __restrict__ bsum, int nb) {
    __shared__ int sm[SCAN_B];
    int t = threadIdx.x;
    int v = (t < nb) ? bsum[t] : 0;
    sm[t] = v; __syncthreads();
    for (int off = 1; off < SCAN_B; off <<= 1) {
        int add = (t >= off) ? sm[t - off] : 0;
        __syncthreads();
        sm[t] += add; __syncthreads();
    }
    if (t < nb) bsum[t] = sm[t] - v;
}
// adds block offsets; writes BOTH rowptr and the place-cursor copy
__global__ void scan3(int* __restrict__ rp, int* __restrict__ ct,
                      const int* __restrict__ bsum, int n) {
    int b = bsum[blockIdx.x];
    #pragma unroll
    for (int k = 0; k < 2; ++k) {
        int idx = blockIdx.x * 2048 + k * SCAN_B + threadIdx.x;
        if (idx < n) { int v = rp[idx] + b; rp[idx] = v; ct[idx] = v; }
    }
}

// range-partitioned placement, 4-deep MLP on the atomic->store chains.
// blocks with blockIdx%NR==r place only keys in range r; per-range ct
// counters stay L2-local. Latency-bound -> batch 4 independent chains.
__global__ void place8(Edges6 e, int* __restrict__ ct, int* __restrict__ pm,
                       int k1, int groupThreads) {
    int r = blockIdx.x & (NR - 1);
    int lo = r * k1, hi = lo + k1;
    int t0 = (blockIdx.x >> 3) * blockDim.x + threadIdx.x;
    #pragma unroll
    for (int k = 0; k < 6; ++k) {
        int kb = e.ctbase[k], ke = e.ctbase[k + 1];
        if (ke <= lo || kb >= hi) continue;        // set doesn't overlap range
        int nk = e.cum[k + 1] - e.cum[k];
        const int* __restrict__ srk = e.src[k];
        const int* __restrict__ dsk = e.dst[k];
        const int st = groupThreads;
        int j = t0;
        for (; j + 3 * st < nk; j += 4 * st) {
            int j0 = j, j1 = j + st, j2 = j + 2 * st, j3 = j + 3 * st;
            int k0 = kb + __builtin_nontemporal_load(srk + j0);
            int k1b = kb + __builtin_nontemporal_load(srk + j1);
            int k2 = kb + __builtin_nontemporal_load(srk + j2);
            int k3 = kb + __builtin_nontemporal_load(srk + j3);
            bool m0 = (k0 >= lo) & (k0 < hi);
            bool m1 = (k1b >= lo) & (k1b < hi);
            bool m2 = (k2 >= lo) & (k2 < hi);
            bool m3 = (k3 >= lo) & (k3 < hi);
            int d0 = 0, d1 = 0, d2 = 0, d3 = 0;
            int p0 = 0, p1 = 0, p2 = 0, p3 = 0;
            if (m0) d0 = __builtin_nontemporal_load(dsk + j0);
            if (m1) d1 = __builtin_nontemporal_load(dsk + j1);
            if (m2) d2 = __builtin_nontemporal_load(dsk + j2);
            if (m3) d3 = __builtin_nontemporal_load(dsk + j3);
            if (m0) p0 = atomicAdd(ct + k0, 1);
            if (m1) p1 = atomicAdd(ct + k1b, 1);
            if (m2) p2 = atomicAdd(ct + k2, 1);
            if (m3) p3 = atomicAdd(ct + k3, 1);
            if (m0) pm[p0] = d0;
            if (m1) pm[p1] = d1;
            if (m2) pm[p2] = d2;
            if (m3) pm[p3] = d3;
        }
        for (; j < nk; j += st) {
            int key = kb + __builtin_nontemporal_load(srk + j);
            if (key >= lo && key < hi) {
                int d = __builtin_nontemporal_load(dsk + j);
                int p = atomicAdd(ct + key, 1);
                pm[p] = d;
            }
        }
    }
}

// ---------- mean-agg of bf16 rows, f32 accumulate, 4-deep MLP ----------
__device__ __forceinline__ void acc8(uint4 v, float* sum) {
    float t[8]; unpack8(v, t);
    #pragma unroll
    for (int k = 0; k < 8; ++k) sum[k] += t[k];
}
// precomputed segment [s,e): lets callers hoist all rowptr loads
__device__ __forceinline__ void agg8se(int s, int e, const int* __restrict__ pm,
                                       const uint4* __restrict__ tgt,
                                       int lane, float w, float* acc) {
    float sum[8] = {0, 0, 0, 0, 0, 0, 0, 0};
    int i = s;
    for (; i + 4 <= e; i += 4) {
        int d0 = pm[i], d1 = pm[i + 1], d2 = pm[i + 2], d3 = pm[i + 3];
        uint4 v0 = tgt[(size_t)d0 * 8 + lane];
        uint4 v1 = tgt[(size_t)d1 * 8 + lane];
        uint4 v2 = tgt[(size_t)d2 * 8 + lane];
        uint4 v3 = tgt[(size_t)d3 * 8 + lane];
        acc8(v0, sum); acc8(v1, sum); acc8(v2, sum); acc8(v3, sum);
    }
    for (; i < e; ++i) {
        uint4 v = tgt[(size_t)pm[i] * 8 + lane];
        acc8(v, sum);
    }
    int deg = e - s;
    float sc = w / (float)(deg > 1 ? deg : 1);
    #pragma unroll
    for (int k = 0; k < 8; ++k) acc[k] += sum[k] * sc;
}

// ---------- fused layer ----------
// mode 0 = seed out, 1 = out += acc, 2 = out = (out+acc)*0.25 and skip next write
__global__ void layer_kernel(
    const int* __restrict__ rp_purch, const int* __restrict__ rp_pby,
    const int* __restrict__ rp_sim,   const int* __restrict__ rp_cop,
    const int* __restrict__ rp_bel,   const int* __restrict__ rp_comp,
    const int* __restrict__ pm,
    const uint4* __restrict__ c16, const uint4* __restrict__ p16,
    const uint4* __restrict__ g16, const uint4* __restrict__ b16,
    uint4* __restrict__ c16n, uint4* __restrict__ p16n,
    float* __restrict__ outc, float* __restrict__ outp,
    int mode)
{
    int t = blockIdx.x * blockDim.x + threadIdx.x;
    int gid = t >> 3;
    int lane = t & 7;
    float acc[8];
    if (gid < NP) {
        int row = gid;
        size_t idx = (size_t)row * 8 + lane;
        // hoist all rowptr loads: 10 independent loads in flight together
        int s0 = rp_pby[row],  e0 = rp_pby[row + 1];
        int s1 = rp_sim[row],  e1 = rp_sim[row + 1];
        int s2 = rp_cop[row],  e2 = rp_cop[row + 1];
        int s3 = rp_bel[row],  e3 = rp_bel[row + 1];
        int s4 = rp_comp[row], e4 = rp_comp[row + 1];
        float base[8]; unpack8(p16[idx], base);
        #pragma unroll
        for (int k = 0; k < 8; ++k) acc[k] = base[k];
        agg8se(s0, e0, pm, c16, lane, 1.0f, acc);
        agg8se(s1, e1, pm, p16, lane, 0.5f, acc);
        agg8se(s2, e2, pm, p16, lane, 0.3f, acc);
        agg8se(s3, e3, pm, g16, lane, 0.2f, acc);
        agg8se(s4, e4, pm, b16, lane, 0.2f, acc);
        if (mode != 2) p16n[idx] = pack8(acc);
        float4* o = (float4*)(outp + (size_t)row * 64 + lane * 8);
        float4 o0, o1;
        if (mode == 0) {
            o0 = make_float4(base[0], base[1], base[2], base[3]);
            o1 = make_float4(base[4], base[5], base[6], base[7]);
        } else { o0 = o[0]; o1 = o[1]; }
        o0.x += acc[0]; o0.y += acc[1]; o0.z += acc[2]; o0.w += acc[3];
        o1.x += acc[4]; o1.y += acc[5]; o1.z += acc[6]; o1.w += acc[7];
        if (mode == 2) {
            o0.x *= 0.25f; o0.y *= 0.25f; o0.z *= 0.25f; o0.w *= 0.25f;
            o1.x *= 0.25f; o1.y *= 0.25f; o1.z *= 0.25f; o1.w *= 0.25f;
        }
        o[0] = o0; o[1] = o1;
    } else if (gid < NP + NC) {
        int row = gid - NP;
        size_t idx = (size_t)row * 8 + lane;
        int s0 = rp_purch[row], e0 = rp_purch[row + 1];
        #pragma unroll
        for (int k = 0; k < 8; ++k) acc[k] = 0.f;
        agg8se(s0, e0, pm, p16, lane, 1.0f, acc);
        if (mode != 2) c16n[idx] = pack8(acc);
        float4* o = (float4*)(outc + (size_t)row * 64 + lane * 8);
        float4 o0, o1;
        if (mode == 0) {
            float base[8]; unpack8(c16[idx], base);
            o0 = make_float4(base[0], base[1], base[2], base[3]);
            o1 = make_float4(base[4], base[5], base[6], base[7]);
        } else { o0 = o[0]; o1 = o[1]; }
        o0.x += acc[0]; o0.y += acc[1]; o0.z += acc[2]; o0.w += acc[3];
        o1.x += acc[4]; o1.y += acc[5]; o1.z += acc[6]; o1.w += acc[7];
        if (mode == 2) {
            o0.x *= 0.25f; o0.y *= 0.25f; o0.z *= 0.25f; o0.w *= 0.25f;
            o1.x *= 0.25f; o1.y *= 0.25f; o1.z *= 0.25f; o1.w *= 0.25f;
        }
        o[0] = o0; o[1] = o1;
    }
}

extern "C" void kernel_launch(void* const* d_in, const int* in_sizes, int n_in,
                              void* d_out, int out_size, void* d_ws, size_t ws_size,
                              hipStream_t stream) {
    const float* cust_w  = (const float*)d_in[0];
    const float* prod_w  = (const float*)d_in[1];
    const float* group_w = (const float*)d_in[2];
    const float* brand_w = (const float*)d_in[3];

    const int n_purch = in_sizes[4];
    const int n_pby   = in_sizes[6];
    const int n_sim   = in_sizes[8];
    const int n_cop   = in_sizes[10];
    const int n_bel   = in_sizes[12];
    const int n_comp  = in_sizes[14];
    const int n_edges[6] = { n_purch, n_pby, n_sim, n_cop, n_bel, n_comp };

    const size_t CSZ = (size_t)NC * 64;
    const size_t PSZ = (size_t)NP * 64;

    // ---- workspace layout ----
    char* base = (char*)d_ws;
    uint4* c16A = (uint4*)base;                 base += (size_t)NC * 128;
    uint4* c16B = (uint4*)base;                 base += (size_t)NC * 128;
    uint4* p16A = (uint4*)base;                 base += (size_t)NP * 128;
    uint4* p16B = (uint4*)base;                 base += (size_t)NP * 128;
    uint4* g16  = (uint4*)base;                 base += (size_t)NG * 128;
    uint4* b16  = (uint4*)base;                 base += (size_t)NB * 128;

    const int RP_PURCH = NC + 1;
    const int RP_OTHER = NP + 1;
    const int RTOT = RP_PURCH + 5 * RP_OTHER;   // 1,050,006

    int* rp_all = (int*)base;                   base += (size_t)RTOT * 4;
    int* ct_all = (int*)base;                   base += (size_t)RTOT * 4;
    long long tot_edges = 0;
    for (int k = 0; k < 6; ++k) tot_edges += n_edges[k];
    int* pm_all = (int*)base;                   base += tot_edges * 4;
    int* bsum   = (int*)base;

    int* rp_purch = rp_all;
    int* rp_pby   = rp_purch + RP_PURCH;
    int* rp_sim   = rp_pby + RP_OTHER;
    int* rp_cop   = rp_sim + RP_OTHER;
    int* rp_bel   = rp_cop + RP_OTHER;
    int* rp_comp  = rp_bel + RP_OTHER;

    float* out_c = (float*)d_out;
    float* out_p = out_c + CSZ;
    float* out_g = out_p + PSZ;
    float* out_b = out_g + (size_t)NG * 64;

    const int BT = 256;

    // ---- fused convert (also copies group/brand f32 outputs) ----
    const long long CVT = (long long)(NC + NP + NG + NB) * 8;
    convert_all<<<cdiv(CVT, BT), BT, 0, stream>>>(
        cust_w, prod_w, group_w, brand_w, c16A, p16A, g16, b16, out_g, out_b);

    // ---- fused CSR build ----
    Edges6 E;
    E.src[0] = (const int*)d_in[4];  E.dst[0] = (const int*)d_in[5];
    E.src[1] = (const int*)d_in[6];  E.dst[1] = (const int*)d_in[7];
    E.src[2] = (const int*)d_in[8];  E.dst[2] = (const int*)d_in[9];
    E.src[3] = (const int*)d_in[10]; E.dst[3] = (const int*)d_in[11];
    E.src[4] = (const int*)d_in[12]; E.dst[4] = (const int*)d_in[13];
    E.src[5] = (const int*)d_in[14]; E.dst[5] = (const int*)d_in[15];
    E.cum[0] = 0;
    for (int k = 0; k < 6; ++k) E.cum[k + 1] = E.cum[k] + n_edges[k];
    E.ctbase[0] = 0;
    E.ctbase[1] = RP_PURCH;
    for (int k = 2; k < 6; ++k) E.ctbase[k] = E.ctbase[k - 1] + RP_OTHER;
    E.ctbase[6] = RTOT;
    const int TOT = E.cum[6];

    hipMemsetAsync(ct_all, 0, (size_t)RTOT * 4, stream);
    count6<<<cdiv(TOT, BT), BT, 0, stream>>>(E, ct_all, TOT);
    {
        int nb = cdiv(RTOT, 2048);   // 513
        scan1<<<nb, SCAN_B, 0, stream>>>(ct_all, rp_all, bsum, RTOT);
        scan2<<<1, SCAN_B, 0, stream>>>(bsum, nb);
        scan3<<<nb, SCAN_B, 0, stream>>>(rp_all, ct_all, bsum, RTOT);
    }
    {
        const int K1 = cdiv(RTOT, NR);           // 131,251 keys per range
        const int GRP = 512;                     // blocks per range-group
        const int groupThreads = GRP * BT;       // stride within a group
        place8<<<NR * GRP, BT, 0, stream>>>(E, ct_all, pm_all, K1, groupThreads);
    }

    // ---- 3 fused layers ----
    const long long LTHREADS = (long long)(NP + NC) * 8;
    layer_kernel<<<cdiv(LTHREADS, BT), BT, 0, stream>>>(
        rp_purch, rp_pby, rp_sim, rp_cop, rp_bel, rp_comp, pm_all,
        c16A, p16A, g16, b16, c16B, p16B, out_c, out_p, 0);
    layer_kernel<<<cdiv(LTHREADS, BT), BT, 0, stream>>>(
        rp_purch, rp_pby, rp_sim, rp_cop, rp_bel, rp_comp, pm_all,
        c16B, p16B, g16, b16, c16A, p16A, out_c, out_p, 1);
    layer_kernel<<<cdiv(LTHREADS, BT), BT, 0, stream>>>(
        rp_purch, rp_pby, rp_sim, rp_cop, rp_bel, rp_comp, pm_all,
        c16A, p16A, g16, b16, c16B, p16B, out_c, out_p, 2);
}

// Round 8
// 880.712 us; speedup vs baseline: 1.6280x; 1.2712x over previous
//
#include <hip/hip_runtime.h>

#define NC 300000
#define NP 150000
#define NG 2000
#define NB 500
#define SCAN_B 1024    // block scans 2048 elements
#define BK_SHIFT 11
#define BK_KEYS 2048   // keys per bucket (= scan block span)
#define NBKT 513       // cdiv(RTOT, BK_KEYS)
#define CH 8192        // edges per msplit chunk

typedef unsigned int u32;

static inline unsigned cdiv(long long a, long long b) { return (unsigned)((a + b - 1) / b); }

// ---------- bf16 helpers ----------
__device__ __forceinline__ float b2f(u32 h) {
    union { u32 u; float f; } c; c.u = h << 16; return c.f;
}
__device__ __forceinline__ u32 f2b(float f) {
    union { float f; u32 u; } c; c.f = f;
    return (c.u + 0x7FFFu + ((c.u >> 16) & 1u)) >> 16;   // RNE
}
__device__ __forceinline__ void unpack8(uint4 v, float* o) {
    o[0] = b2f(v.x & 0xFFFFu); o[1] = b2f(v.x >> 16);
    o[2] = b2f(v.y & 0xFFFFu); o[3] = b2f(v.y >> 16);
    o[4] = b2f(v.z & 0xFFFFu); o[5] = b2f(v.z >> 16);
    o[6] = b2f(v.w & 0xFFFFu); o[7] = b2f(v.w >> 16);
}
__device__ __forceinline__ uint4 pack8(const float* a) {
    uint4 v;
    v.x = f2b(a[0]) | (f2b(a[1]) << 16);
    v.y = f2b(a[2]) | (f2b(a[3]) << 16);
    v.z = f2b(a[4]) | (f2b(a[5]) << 16);
    v.w = f2b(a[6]) | (f2b(a[7]) << 16);
    return v;
}

// ---------- fused f32->bf16 convert of all 4 tables (+ f32 copy for g/b outputs) ----------
__global__ void convert_all(const float* __restrict__ cw, const float* __restrict__ pw,
                            const float* __restrict__ gw, const float* __restrict__ bw,
                            uint4* __restrict__ c16, uint4* __restrict__ p16,
                            uint4* __restrict__ g16, uint4* __restrict__ b16,
                            float* __restrict__ outg, float* __restrict__ outb) {
    const int C8 = NC * 8, P8 = NP * 8, G8 = NG * 8, B8 = NB * 8;
    int i = blockIdx.x * blockDim.x + threadIdx.x;
    const float* in; uint4* out16; float* cpy = nullptr; int j;
    if (i < C8)                         { in = cw; out16 = c16; j = i; }
    else if ((j = i - C8) < P8)         { in = pw; out16 = p16; }
    else if ((j = i - C8 - P8) < G8)    { in = gw; out16 = g16; cpy = outg; }
    else if ((j = i - C8 - P8 - G8) < B8){ in = bw; out16 = b16; cpy = outb; }
    else return;
    const float4* p = (const float4*)(in + (size_t)j * 8);
    float4 a = p[0], b = p[1];
    float t[8] = { a.x, a.y, a.z, a.w, b.x, b.y, b.z, b.w };
    out16[j] = pack8(t);
    if (cpy) { float4* q = (float4*)(cpy + (size_t)j * 8); q[0] = a; q[1] = b; }
}

// ---------- fused CSR build over all 6 edge sets ----------
struct Edges6 {
    const int* src[6];
    const int* dst[6];
    int cum[7];      // cumulative edge-count offsets (cum[6] = total)
    int ctbase[7];   // base key of each set's count segment (ctbase[6] = RTOT)
};

__global__ void count6(Edges6 e, int* __restrict__ ct, int total) {
    int id = blockIdx.x * blockDim.x + threadIdx.x;
    if (id >= total) return;
    int k = 0;
    #pragma unroll
    for (int q = 1; q < 6; ++q) k += (id >= e.cum[q]);
    int j = id - e.cum[k];
    atomicAdd(ct + e.ctbase[k] + e.src[k][j], 1);
}

// ---------- global exclusive scan, 2048 elems/block ----------
__global__ void scan1(const int* __restrict__ in, int* __restrict__ out,
                      int* __restrict__ bsum, int n) {
    __shared__ int sm[SCAN_B];
    int t = threadIdx.x;
    int i0 = blockIdx.x * 2048 + 2 * t, i1 = i0 + 1;
    int v0 = (i0 < n) ? in[i0] : 0;
    int v1 = (i1 < n) ? in[i1] : 0;
    int pair = v0 + v1;
    sm[t] = pair; __syncthreads();
    for (int off = 1; off < SCAN_B; off <<= 1) {
        int add = (t >= off) ? sm[t - off] : 0;
        __syncthreads();
        sm[t] += add; __syncthreads();
    }
    int excl = sm[t] - pair;
    if (i0 < n) out[i0] = excl;
    if (i1 < n) out[i1] = excl + v0;
    if (t == SCAN_B - 1) bsum[blockIdx.x] = sm[t];
}
__global__ void scan2(int* __restrict__ bsum, int nb) {
    __shared__ int sm[SCAN_B];
    int t = threadIdx.x;
    int v = (t < nb) ? bsum[t] : 0;
    sm[t] = v; __syncthreads();
    for (int off = 1; off < SCAN_B; off <<= 1) {
        int add = (t >= off) ? sm[t - off] : 0;
        __syncthreads();
        sm[t] += add; __syncthreads();
    }
    if (t < nb) bsum[t] = sm[t] - v;
}
// adds block offsets into rp; emits per-bucket claim cursors (rp at bucket starts)
__global__ void scan3(int* __restrict__ rp, int* __restrict__ gcur,
                      const int* __restrict__ bsum, int n) {
    int b = bsum[blockIdx.x];
    #pragma unroll
    for (int k = 0; k < 2; ++k) {
        int idx = blockIdx.x * 2048 + k * SCAN_B + threadIdx.x;
        if (idx < n) {
            int v = rp[idx] + b;
            rp[idx] = v;
            if ((idx & (BK_KEYS - 1)) == 0) gcur[idx >> BK_SHIFT] = v;
        }
    }
}

// ---------- pass 1: 3-phase multisplit into NBKT buckets, dense stage writes ----------
// stage word = (key & 2047) << 19 | dst   (dst < 2^19)
__global__ void msplit(Edges6 e, int* __restrict__ gcur, u32* __restrict__ stage, int total) {
    __shared__ int hist[NBKT];
    __shared__ int bse[NBKT];
    int t = threadIdx.x;
    int j0 = blockIdx.x * CH;
    for (int b = t; b < NBKT; b += blockDim.x) hist[b] = 0;
    __syncthreads();
    // phase 1: LDS histogram of this chunk
    #pragma unroll 4
    for (int q = 0; q < CH / 256; ++q) {
        int j = j0 + q * 256 + t;
        if (j < total) {
            int k = 0;
            #pragma unroll
            for (int qq = 1; qq < 6; ++qq) k += (j >= e.cum[qq]);
            int key = e.ctbase[k] + __builtin_nontemporal_load(e.src[k] + (j - e.cum[k]));
            atomicAdd(&hist[key >> BK_SHIFT], 1);
        }
    }
    __syncthreads();
    // phase 2: claim one contiguous run per non-empty bucket
    for (int b = t; b < NBKT; b += blockDim.x) {
        int c = hist[b];
        bse[b] = (c > 0) ? atomicAdd(gcur + b, c) : 0;
        hist[b] = 0;
    }
    __syncthreads();
    // phase 3: re-read chunk (L2-hot), assign offsets in LDS, dense stage writes
    #pragma unroll 4
    for (int q = 0; q < CH / 256; ++q) {
        int j = j0 + q * 256 + t;
        if (j < total) {
            int k = 0;
            #pragma unroll
            for (int qq = 1; qq < 6; ++qq) k += (j >= e.cum[qq]);
            int jj = j - e.cum[k];
            int key = e.ctbase[k] + __builtin_nontemporal_load(e.src[k] + jj);
            int d = __builtin_nontemporal_load(e.dst[k] + jj);
            int b = key >> BK_SHIFT;
            int off = atomicAdd(&hist[b], 1);
            stage[bse[b] + off] = ((u32)(key & (BK_KEYS - 1)) << 19) | (u32)d;
        }
    }
}

// ---------- pass 2: one block per bucket, LDS cursors -> pm (in-L2 window) ----------
__global__ void sortb(const int* __restrict__ rp, const u32* __restrict__ stage,
                      int* __restrict__ pm, int rtot, int tot) {
    __shared__ int cur[BK_KEYS];
    int b = blockIdx.x, t = threadIdx.x;
    int k0 = b << BK_SHIFT;
    int base = rp[k0];
    int kend = k0 + BK_KEYS;
    int end = (kend < rtot) ? rp[kend] : tot;
    for (int q = t; q < BK_KEYS; q += blockDim.x) {
        int ki = k0 + q;
        cur[q] = (ki < rtot) ? rp[ki] : tot;
    }
    __syncthreads();
    for (int i = base + t; i < end; i += blockDim.x) {
        u32 w = stage[i];
        int off = atomicAdd(&cur[w >> 19], 1);
        pm[off] = (int)(w & 0x7FFFFu);
    }
}

// ---------- mean-agg of bf16 rows, f32 accumulate, 4-deep MLP ----------
__device__ __forceinline__ void acc8(uint4 v, float* sum) {
    float t[8]; unpack8(v, t);
    #pragma unroll
    for (int k = 0; k < 8; ++k) sum[k] += t[k];
}
__device__ __forceinline__ void agg8se(int s, int e, const int* __restrict__ pm,
                                       const uint4* __restrict__ tgt,
                                       int lane, float w, float* acc) {
    float sum[8] = {0, 0, 0, 0, 0, 0, 0, 0};
    int i = s;
    for (; i + 4 <= e; i += 4) {
        int d0 = pm[i], d1 = pm[i + 1], d2 = pm[i + 2], d3 = pm[i + 3];
        uint4 v0 = tgt[(size_t)d0 * 8 + lane];
        uint4 v1 = tgt[(size_t)d1 * 8 + lane];
        uint4 v2 = tgt[(size_t)d2 * 8 + lane];
        uint4 v3 = tgt[(size_t)d3 * 8 + lane];
        acc8(v0, sum); acc8(v1, sum); acc8(v2, sum); acc8(v3, sum);
    }
    for (; i < e; ++i) {
        uint4 v = tgt[(size_t)pm[i] * 8 + lane];
        acc8(v, sum);
    }
    int deg = e - s;
    float sc = w / (float)(deg > 1 ? deg : 1);
    #pragma unroll
    for (int k = 0; k < 8; ++k) acc[k] += sum[k] * sc;
}

// ---------- fused layer ----------
// mode 0 = seed out, 1 = out += acc, 2 = out = (out+acc)*0.25 and skip next write
__global__ void layer_kernel(
    const int* __restrict__ rp_purch, const int* __restrict__ rp_pby,
    const int* __restrict__ rp_sim,   const int* __restrict__ rp_cop,
    const int* __restrict__ rp_bel,   const int* __restrict__ rp_comp,
    const int* __restrict__ pm,
    const uint4* __restrict__ c16, const uint4* __restrict__ p16,
    const uint4* __restrict__ g16, const uint4* __restrict__ b16,
    uint4* __restrict__ c16n, uint4* __restrict__ p16n,
    float* __restrict__ outc, float* __restrict__ outp,
    int mode)
{
    int t = blockIdx.x * blockDim.x + threadIdx.x;
    int gid = t >> 3;
    int lane = t & 7;
    float acc[8];
    if (gid < NP) {
        int row = gid;
        size_t idx = (size_t)row * 8 + lane;
        int s0 = rp_pby[row],  e0 = rp_pby[row + 1];
        int s1 = rp_sim[row],  e1 = rp_sim[row + 1];
        int s2 = rp_cop[row],  e2 = rp_cop[row + 1];
        int s3 = rp_bel[row],  e3 = rp_bel[row + 1];
        int s4 = rp_comp[row], e4 = rp_comp[row + 1];
        float base[8]; unpack8(p16[idx], base);
        #pragma unroll
        for (int k = 0; k < 8; ++k) acc[k] = base[k];
        agg8se(s0, e0, pm, c16, lane, 1.0f, acc);
        agg8se(s1, e1, pm, p16, lane, 0.5f, acc);
        agg8se(s2, e2, pm, p16, lane, 0.3f, acc);
        agg8se(s3, e3, pm, g16, lane, 0.2f, acc);
        agg8se(s4, e4, pm, b16, lane, 0.2f, acc);
        if (mode != 2) p16n[idx] = pack8(acc);
        float4* o = (float4*)(outp + (size_t)row * 64 + lane * 8);
        float4 o0, o1;
        if (mode == 0) {
            o0 = make_float4(base[0], base[1], base[2], base[3]);
            o1 = make_float4(base[4], base[5], base[6], base[7]);
        } else { o0 = o[0]; o1 = o[1]; }
        o0.x += acc[0]; o0.y += acc[1]; o0.z += acc[2]; o0.w += acc[3];
        o1.x += acc[4]; o1.y += acc[5]; o1.z += acc[6]; o1.w += acc[7];
        if (mode == 2) {
            o0.x *= 0.25f; o0.y *= 0.25f; o0.z *= 0.25f; o0.w *= 0.25f;
            o1.x *= 0.25f; o1.y *= 0.25f; o1.z *= 0.25f; o1.w *= 0.25f;
        }
        o[0] = o0; o[1] = o1;
    } else if (gid < NP + NC) {
        int row = gid - NP;
        size_t idx = (size_t)row * 8 + lane;
        int s0 = rp_purch[row], e0 = rp_purch[row + 1];
        #pragma unroll
        for (int k = 0; k < 8; ++k) acc[k] = 0.f;
        agg8se(s0, e0, pm, p16, lane, 1.0f, acc);
        if (mode != 2) c16n[idx] = pack8(acc);
        float4* o = (float4*)(outc + (size_t)row * 64 + lane * 8);
        float4 o0, o1;
        if (mode == 0) {
            float base[8]; unpack8(c16[idx], base);
            o0 = make_float4(base[0], base[1], base[2], base[3]);
            o1 = make_float4(base[4], base[5], base[6], base[7]);
        } else { o0 = o[0]; o1 = o[1]; }
        o0.x += acc[0]; o0.y += acc[1]; o0.z += acc[2]; o0.w += acc[3];
        o1.x += acc[4]; o1.y += acc[5]; o1.z += acc[6]; o1.w += acc[7];
        if (mode == 2) {
            o0.x *= 0.25f; o0.y *= 0.25f; o0.z *= 0.25f; o0.w *= 0.25f;
            o1.x *= 0.25f; o1.y *= 0.25f; o1.z *= 0.25f; o1.w *= 0.25f;
        }
        o[0] = o0; o[1] = o1;
    }
}

extern "C" void kernel_launch(void* const* d_in, const int* in_sizes, int n_in,
                              void* d_out, int out_size, void* d_ws, size_t ws_size,
                              hipStream_t stream) {
    const float* cust_w  = (const float*)d_in[0];
    const float* prod_w  = (const float*)d_in[1];
    const float* group_w = (const float*)d_in[2];
    const float* brand_w = (const float*)d_in[3];

    const int n_purch = in_sizes[4];
    const int n_pby   = in_sizes[6];
    const int n_sim   = in_sizes[8];
    const int n_cop   = in_sizes[10];
    const int n_bel   = in_sizes[12];
    const int n_comp  = in_sizes[14];
    const int n_edges[6] = { n_purch, n_pby, n_sim, n_cop, n_bel, n_comp };

    const size_t CSZ = (size_t)NC * 64;
    const size_t PSZ = (size_t)NP * 64;

    // ---- workspace layout ----
    char* base = (char*)d_ws;
    uint4* c16A = (uint4*)base;                 base += (size_t)NC * 128;
    uint4* c16B = (uint4*)base;                 base += (size_t)NC * 128;
    uint4* p16A = (uint4*)base;                 base += (size_t)NP * 128;
    uint4* p16B = (uint4*)base;                 base += (size_t)NP * 128;
    uint4* g16  = (uint4*)base;                 base += (size_t)NG * 128;
    uint4* b16  = (uint4*)base;                 base += (size_t)NB * 128;

    const int RP_PURCH = NC + 1;
    const int RP_OTHER = NP + 1;
    const int RTOT = RP_PURCH + 5 * RP_OTHER;   // 1,050,006  (NBKT*2048 >= RTOT)

    int* rp_all = (int*)base;                   base += (size_t)RTOT * 4;
    int* ct_all = (int*)base;                   base += (size_t)RTOT * 4;
    long long tot_edges = 0;
    for (int k = 0; k < 6; ++k) tot_edges += n_edges[k];
    int* pm_all = (int*)base;                   base += tot_edges * 4;
    u32* stage  = (u32*)base;                   base += tot_edges * 4;
    int* gcur   = (int*)base;                   base += (size_t)NBKT * 4;
    int* bsum   = (int*)base;

    int* rp_purch = rp_all;
    int* rp_pby   = rp_purch + RP_PURCH;
    int* rp_sim   = rp_pby + RP_OTHER;
    int* rp_cop   = rp_sim + RP_OTHER;
    int* rp_bel   = rp_cop + RP_OTHER;
    int* rp_comp  = rp_bel + RP_OTHER;

    float* out_c = (float*)d_out;
    float* out_p = out_c + CSZ;
    float* out_g = out_p + PSZ;
    float* out_b = out_g + (size_t)NG * 64;

    const int BT = 256;

    // ---- fused convert (also copies group/brand f32 outputs) ----
    const long long CVT = (long long)(NC + NP + NG + NB) * 8;
    convert_all<<<cdiv(CVT, BT), BT, 0, stream>>>(
        cust_w, prod_w, group_w, brand_w, c16A, p16A, g16, b16, out_g, out_b);

    // ---- fused CSR build: count -> scan -> multisplit -> bucket place ----
    Edges6 E;
    E.src[0] = (const int*)d_in[4];  E.dst[0] = (const int*)d_in[5];
    E.src[1] = (const int*)d_in[6];  E.dst[1] = (const int*)d_in[7];
    E.src[2] = (const int*)d_in[8];  E.dst[2] = (const int*)d_in[9];
    E.src[3] = (const int*)d_in[10]; E.dst[3] = (const int*)d_in[11];
    E.src[4] = (const int*)d_in[12]; E.dst[4] = (const int*)d_in[13];
    E.src[5] = (const int*)d_in[14]; E.dst[5] = (const int*)d_in[15];
    E.cum[0] = 0;
    for (int k = 0; k < 6; ++k) E.cum[k + 1] = E.cum[k] + n_edges[k];
    E.ctbase[0] = 0;
    E.ctbase[1] = RP_PURCH;
    for (int k = 2; k < 6; ++k) E.ctbase[k] = E.ctbase[k - 1] + RP_OTHER;
    E.ctbase[6] = RTOT;
    const int TOT = E.cum[6];

    hipMemsetAsync(ct_all, 0, (size_t)RTOT * 4, stream);
    count6<<<cdiv(TOT, BT), BT, 0, stream>>>(E, ct_all, TOT);
    {
        int nb = cdiv(RTOT, 2048);   // 513 == NBKT
        scan1<<<nb, SCAN_B, 0, stream>>>(ct_all, rp_all, bsum, RTOT);
        scan2<<<1, SCAN_B, 0, stream>>>(bsum, nb);
        scan3<<<nb, SCAN_B, 0, stream>>>(rp_all, gcur, bsum, RTOT);
    }
    msplit<<<cdiv(TOT, CH), BT, 0, stream>>>(E, gcur, stage, TOT);
    sortb<<<NBKT, 512, 0, stream>>>(rp_all, stage, pm_all, RTOT, TOT);

    // ---- 3 fused layers ----
    const long long LTHREADS = (long long)(NP + NC) * 8;
    layer_kernel<<<cdiv(LTHREADS, BT), BT, 0, stream>>>(
        rp_purch, rp_pby, rp_sim, rp_cop, rp_bel, rp_comp, pm_all,
        c16A, p16A, g16, b16, c16B, p16B, out_c, out_p, 0);
    layer_kernel<<<cdiv(LTHREADS, BT), BT, 0, stream>>>(
        rp_purch, rp_pby, rp_sim, rp_cop, rp_bel, rp_comp, pm_all,
        c16B, p16B, g16, b16, c16A, p16A, out_c, out_p, 1);
    layer_kernel<<<cdiv(LTHREADS, BT), BT, 0, stream>>>(
        rp_purch, rp_pby, rp_sim, rp_cop, rp_bel, rp_comp, pm_all,
        c16A, p16A, g16, b16, c16B, p16B, out_c, out_p, 2);
}

// Round 9
// 683.782 us; speedup vs baseline: 2.0968x; 1.2880x over previous
//
#include <hip/hip_runtime.h>

#define NC 300000
#define NP 150000
#define NG 2000
#define NB 500
#define SCAN_B 1024
#define BK_SHIFT 11
#define BK_KEYS 2048   // keys per bucket
#define NBKT 513       // cdiv(RTOT, BK_KEYS)
#define CH 8192        // edges per chunk (bcount/msplit)

typedef unsigned int u32;

static inline unsigned cdiv(long long a, long long b) { return (unsigned)((a + b - 1) / b); }

// ---------- bf16 helpers ----------
__device__ __forceinline__ float b2f(u32 h) {
    union { u32 u; float f; } c; c.u = h << 16; return c.f;
}
__device__ __forceinline__ u32 f2b(float f) {
    union { float f; u32 u; } c; c.f = f;
    return (c.u + 0x7FFFu + ((c.u >> 16) & 1u)) >> 16;   // RNE
}
__device__ __forceinline__ void unpack8(uint4 v, float* o) {
    o[0] = b2f(v.x & 0xFFFFu); o[1] = b2f(v.x >> 16);
    o[2] = b2f(v.y & 0xFFFFu); o[3] = b2f(v.y >> 16);
    o[4] = b2f(v.z & 0xFFFFu); o[5] = b2f(v.z >> 16);
    o[6] = b2f(v.w & 0xFFFFu); o[7] = b2f(v.w >> 16);
}
__device__ __forceinline__ uint4 pack8(const float* a) {
    uint4 v;
    v.x = f2b(a[0]) | (f2b(a[1]) << 16);
    v.y = f2b(a[2]) | (f2b(a[3]) << 16);
    v.z = f2b(a[4]) | (f2b(a[5]) << 16);
    v.w = f2b(a[6]) | (f2b(a[7]) << 16);
    return v;
}

// ---------- fused f32->bf16 convert of all 4 tables (+ f32 copy for g/b outputs) ----------
__global__ void convert_all(const float* __restrict__ cw, const float* __restrict__ pw,
                            const float* __restrict__ gw, const float* __restrict__ bw,
                            uint4* __restrict__ c16, uint4* __restrict__ p16,
                            uint4* __restrict__ g16, uint4* __restrict__ b16,
                            float* __restrict__ outg, float* __restrict__ outb) {
    const int C8 = NC * 8, P8 = NP * 8, G8 = NG * 8, B8 = NB * 8;
    int i = blockIdx.x * blockDim.x + threadIdx.x;
    const float* in; uint4* out16; float* cpy = nullptr; int j;
    if (i < C8)                         { in = cw; out16 = c16; j = i; }
    else if ((j = i - C8) < P8)         { in = pw; out16 = p16; }
    else if ((j = i - C8 - P8) < G8)    { in = gw; out16 = g16; cpy = outg; }
    else if ((j = i - C8 - P8 - G8) < B8){ in = bw; out16 = b16; cpy = outb; }
    else return;
    const float4* p = (const float4*)(in + (size_t)j * 8);
    float4 a = p[0], b = p[1];
    float t[8] = { a.x, a.y, a.z, a.w, b.x, b.y, b.z, b.w };
    out16[j] = pack8(t);
    if (cpy) { float4* q = (float4*)(cpy + (size_t)j * 8); q[0] = a; q[1] = b; }
}

// ---------- fused CSR build over all 6 edge sets ----------
struct Edges6 {
    const int* src[6];
    const int* dst[6];
    int cum[7];      // cumulative edge-count offsets (cum[6] = total)
    int ctbase[7];   // base key of each set's segment (ctbase[6] = RTOT)
};

// ---------- stage A: bucket-granularity counts via LDS histogram ----------
__global__ void bcount(Edges6 e, int* __restrict__ gcount, int total) {
    __shared__ int hist[NBKT];
    int t = threadIdx.x;
    int j0 = blockIdx.x * CH;
    for (int b = t; b < NBKT; b += blockDim.x) hist[b] = 0;
    __syncthreads();
    #pragma unroll 4
    for (int q = 0; q < CH / 256; ++q) {
        int j = j0 + q * 256 + t;
        if (j < total) {
            int k = 0;
            #pragma unroll
            for (int qq = 1; qq < 6; ++qq) k += (j >= e.cum[qq]);
            int key = e.ctbase[k] + __builtin_nontemporal_load(e.src[k] + (j - e.cum[k]));
            atomicAdd(&hist[key >> BK_SHIFT], 1);
        }
    }
    __syncthreads();
    for (int b = t; b < NBKT; b += blockDim.x) {
        int c = hist[b];
        if (c > 0) atomicAdd(gcount + b, c);
    }
}

// ---------- stage B: one-block scan of 513 bucket counts -> gbase, gcur ----------
__global__ void bscan(const int* __restrict__ gcount, int* __restrict__ gbase,
                      int* __restrict__ gcur, int nb) {
    __shared__ int sm[SCAN_B];
    int t = threadIdx.x;
    int v = (t < nb) ? gcount[t] : 0;
    sm[t] = v; __syncthreads();
    for (int off = 1; off < SCAN_B; off <<= 1) {
        int add = (t >= off) ? sm[t - off] : 0;
        __syncthreads();
        sm[t] += add; __syncthreads();
    }
    int excl = sm[t] - v;
    if (t < nb) { gbase[t] = excl; gcur[t] = excl; }
    if (t == nb - 1) gbase[nb] = sm[t];
}

// ---------- stage C: 3-phase multisplit into buckets, dense stage writes ----------
// stage word = (key & 2047) << 19 | dst   (dst < 2^19)
__global__ void msplit(Edges6 e, int* __restrict__ gcur, u32* __restrict__ stage, int total) {
    __shared__ int hist[NBKT];
    __shared__ int bse[NBKT];
    int t = threadIdx.x;
    int j0 = blockIdx.x * CH;
    for (int b = t; b < NBKT; b += blockDim.x) hist[b] = 0;
    __syncthreads();
    #pragma unroll 4
    for (int q = 0; q < CH / 256; ++q) {
        int j = j0 + q * 256 + t;
        if (j < total) {
            int k = 0;
            #pragma unroll
            for (int qq = 1; qq < 6; ++qq) k += (j >= e.cum[qq]);
            int key = e.ctbase[k] + __builtin_nontemporal_load(e.src[k] + (j - e.cum[k]));
            atomicAdd(&hist[key >> BK_SHIFT], 1);
        }
    }
    __syncthreads();
    for (int b = t; b < NBKT; b += blockDim.x) {
        int c = hist[b];
        bse[b] = (c > 0) ? atomicAdd(gcur + b, c) : 0;
        hist[b] = 0;
    }
    __syncthreads();
    #pragma unroll 4
    for (int q = 0; q < CH / 256; ++q) {
        int j = j0 + q * 256 + t;
        if (j < total) {
            int k = 0;
            #pragma unroll
            for (int qq = 1; qq < 6; ++qq) k += (j >= e.cum[qq]);
            int jj = j - e.cum[k];
            int key = e.ctbase[k] + __builtin_nontemporal_load(e.src[k] + jj);
            int d = __builtin_nontemporal_load(e.dst[k] + jj);
            int b = key >> BK_SHIFT;
            int off = atomicAdd(&hist[b], 1);
            stage[bse[b] + off] = ((u32)(key & (BK_KEYS - 1)) << 19) | (u32)d;
        }
    }
}

// ---------- stage D: per-bucket LDS histogram+scan -> rowptr slice + place pm ----------
__global__ void sortb(const int* __restrict__ gbase, const u32* __restrict__ stage,
                      int* __restrict__ pm, int* __restrict__ rp, int rtot) {
    __shared__ int cur[BK_KEYS];
    __shared__ int part[512];
    int b = blockIdx.x, t = threadIdx.x;
    int k0 = b << BK_SHIFT;
    int base = gbase[b], end = gbase[b + 1];
    for (int q = t; q < BK_KEYS; q += 512) cur[q] = 0;
    __syncthreads();
    // histogram the bucket's staged keys
    for (int i = base + t; i < end; i += 512)
        atomicAdd(&cur[stage[i] >> 19], 1);
    __syncthreads();
    // block-local exclusive scan (512 threads x 4 keys)
    int a0 = cur[4 * t], a1 = cur[4 * t + 1], a2 = cur[4 * t + 2], a3 = cur[4 * t + 3];
    int s = a0 + a1 + a2 + a3;
    part[t] = s; __syncthreads();
    for (int off = 1; off < 512; off <<= 1) {
        int add = (t >= off) ? part[t - off] : 0;
        __syncthreads();
        part[t] += add; __syncthreads();
    }
    int c0 = base + part[t] - s;
    int c1 = c0 + a0, c2 = c1 + a1, c3 = c2 + a2;
    cur[4 * t] = c0; cur[4 * t + 1] = c1; cur[4 * t + 2] = c2; cur[4 * t + 3] = c3;
    // dense rowptr slice write
    int ki = k0 + 4 * t;
    if (ki + 3 < rtot) {
        *(int4*)(rp + ki) = make_int4(c0, c1, c2, c3);
    } else {
        if (ki     < rtot) rp[ki]     = c0;
        if (ki + 1 < rtot) rp[ki + 1] = c1;
        if (ki + 2 < rtot) rp[ki + 2] = c2;
        if (ki + 3 < rtot) rp[ki + 3] = c3;
    }
    __syncthreads();
    // place into pm within the bucket's dense window
    for (int i = base + t; i < end; i += 512) {
        u32 w = stage[i];
        int off = atomicAdd(&cur[w >> 19], 1);
        pm[off] = (int)(w & 0x7FFFFu);
    }
}

// ---------- mean-agg of bf16 rows, f32 accumulate, 4-deep MLP ----------
__device__ __forceinline__ void acc8(uint4 v, float* sum) {
    float t[8]; unpack8(v, t);
    #pragma unroll
    for (int k = 0; k < 8; ++k) sum[k] += t[k];
}
__device__ __forceinline__ void agg8se(int s, int e, const int* __restrict__ pm,
                                       const uint4* __restrict__ tgt,
                                       int lane, float w, float* acc) {
    float sum[8] = {0, 0, 0, 0, 0, 0, 0, 0};
    int i = s;
    for (; i + 4 <= e; i += 4) {
        int d0 = pm[i], d1 = pm[i + 1], d2 = pm[i + 2], d3 = pm[i + 3];
        uint4 v0 = tgt[(size_t)d0 * 8 + lane];
        uint4 v1 = tgt[(size_t)d1 * 8 + lane];
        uint4 v2 = tgt[(size_t)d2 * 8 + lane];
        uint4 v3 = tgt[(size_t)d3 * 8 + lane];
        acc8(v0, sum); acc8(v1, sum); acc8(v2, sum); acc8(v3, sum);
    }
    for (; i < e; ++i) {
        uint4 v = tgt[(size_t)pm[i] * 8 + lane];
        acc8(v, sum);
    }
    int deg = e - s;
    float sc = w / (float)(deg > 1 ? deg : 1);
    #pragma unroll
    for (int k = 0; k < 8; ++k) acc[k] += sum[k] * sc;
}

// ---------- fused layer ----------
// mode 0 = seed out, 1 = out += acc, 2 = out = (out+acc)*0.25 and skip next write
__global__ void layer_kernel(
    const int* __restrict__ rp_purch, const int* __restrict__ rp_pby,
    const int* __restrict__ rp_sim,   const int* __restrict__ rp_cop,
    const int* __restrict__ rp_bel,   const int* __restrict__ rp_comp,
    const int* __restrict__ pm,
    const uint4* __restrict__ c16, const uint4* __restrict__ p16,
    const uint4* __restrict__ g16, const uint4* __restrict__ b16,
    uint4* __restrict__ c16n, uint4* __restrict__ p16n,
    float* __restrict__ outc, float* __restrict__ outp,
    int mode)
{
    int t = blockIdx.x * blockDim.x + threadIdx.x;
    int gid = t >> 3;
    int lane = t & 7;
    float acc[8];
    if (gid < NP) {
        int row = gid;
        size_t idx = (size_t)row * 8 + lane;
        int s0 = rp_pby[row],  e0 = rp_pby[row + 1];
        int s1 = rp_sim[row],  e1 = rp_sim[row + 1];
        int s2 = rp_cop[row],  e2 = rp_cop[row + 1];
        int s3 = rp_bel[row],  e3 = rp_bel[row + 1];
        int s4 = rp_comp[row], e4 = rp_comp[row + 1];
        float base[8]; unpack8(p16[idx], base);
        #pragma unroll
        for (int k = 0; k < 8; ++k) acc[k] = base[k];
        agg8se(s0, e0, pm, c16, lane, 1.0f, acc);
        agg8se(s1, e1, pm, p16, lane, 0.5f, acc);
        agg8se(s2, e2, pm, p16, lane, 0.3f, acc);
        agg8se(s3, e3, pm, g16, lane, 0.2f, acc);
        agg8se(s4, e4, pm, b16, lane, 0.2f, acc);
        if (mode != 2) p16n[idx] = pack8(acc);
        float4* o = (float4*)(outp + (size_t)row * 64 + lane * 8);
        float4 o0, o1;
        if (mode == 0) {
            o0 = make_float4(base[0], base[1], base[2], base[3]);
            o1 = make_float4(base[4], base[5], base[6], base[7]);
        } else { o0 = o[0]; o1 = o[1]; }
        o0.x += acc[0]; o0.y += acc[1]; o0.z += acc[2]; o0.w += acc[3];
        o1.x += acc[4]; o1.y += acc[5]; o1.z += acc[6]; o1.w += acc[7];
        if (mode == 2) {
            o0.x *= 0.25f; o0.y *= 0.25f; o0.z *= 0.25f; o0.w *= 0.25f;
            o1.x *= 0.25f; o1.y *= 0.25f; o1.z *= 0.25f; o1.w *= 0.25f;
        }
        o[0] = o0; o[1] = o1;
    } else if (gid < NP + NC) {
        int row = gid - NP;
        size_t idx = (size_t)row * 8 + lane;
        int s0 = rp_purch[row], e0 = rp_purch[row + 1];
        #pragma unroll
        for (int k = 0; k < 8; ++k) acc[k] = 0.f;
        agg8se(s0, e0, pm, p16, lane, 1.0f, acc);
        if (mode != 2) c16n[idx] = pack8(acc);
        float4* o = (float4*)(outc + (size_t)row * 64 + lane * 8);
        float4 o0, o1;
        if (mode == 0) {
            float base[8]; unpack8(c16[idx], base);
            o0 = make_float4(base[0], base[1], base[2], base[3]);
            o1 = make_float4(base[4], base[5], base[6], base[7]);
        } else { o0 = o[0]; o1 = o[1]; }
        o0.x += acc[0]; o0.y += acc[1]; o0.z += acc[2]; o0.w += acc[3];
        o1.x += acc[4]; o1.y += acc[5]; o1.z += acc[6]; o1.w += acc[7];
        if (mode == 2) {
            o0.x *= 0.25f; o0.y *= 0.25f; o0.z *= 0.25f; o0.w *= 0.25f;
            o1.x *= 0.25f; o1.y *= 0.25f; o1.z *= 0.25f; o1.w *= 0.25f;
        }
        o[0] = o0; o[1] = o1;
    }
}

extern "C" void kernel_launch(void* const* d_in, const int* in_sizes, int n_in,
                              void* d_out, int out_size, void* d_ws, size_t ws_size,
                              hipStream_t stream) {
    const float* cust_w  = (const float*)d_in[0];
    const float* prod_w  = (const float*)d_in[1];
    const float* group_w = (const float*)d_in[2];
    const float* brand_w = (const float*)d_in[3];

    const int n_purch = in_sizes[4];
    const int n_pby   = in_sizes[6];
    const int n_sim   = in_sizes[8];
    const int n_cop   = in_sizes[10];
    const int n_bel   = in_sizes[12];
    const int n_comp  = in_sizes[14];
    const int n_edges[6] = { n_purch, n_pby, n_sim, n_cop, n_bel, n_comp };

    const size_t CSZ = (size_t)NC * 64;
    const size_t PSZ = (size_t)NP * 64;

    // ---- workspace layout ----
    char* base = (char*)d_ws;
    uint4* c16A = (uint4*)base;                 base += (size_t)NC * 128;
    uint4* c16B = (uint4*)base;                 base += (size_t)NC * 128;
    uint4* p16A = (uint4*)base;                 base += (size_t)NP * 128;
    uint4* p16B = (uint4*)base;                 base += (size_t)NP * 128;
    uint4* g16  = (uint4*)base;                 base += (size_t)NG * 128;
    uint4* b16  = (uint4*)base;                 base += (size_t)NB * 128;

    const int RP_PURCH = NC + 1;
    const int RP_OTHER = NP + 1;
    const int RTOT = RP_PURCH + 5 * RP_OTHER;   // 1,050,006 (NBKT*2048 >= RTOT)

    int* rp_all = (int*)base;                   base += (size_t)RTOT * 4;
    long long tot_edges = 0;
    for (int k = 0; k < 6; ++k) tot_edges += n_edges[k];
    int* pm_all = (int*)base;                   base += tot_edges * 4;
    u32* stage  = (u32*)base;                   base += tot_edges * 4;
    int* gcount = (int*)base;                   base += (size_t)NBKT * 4;
    int* gbase  = (int*)base;                   base += (size_t)(NBKT + 1) * 4;
    int* gcur   = (int*)base;

    int* rp_purch = rp_all;
    int* rp_pby   = rp_purch + RP_PURCH;
    int* rp_sim   = rp_pby + RP_OTHER;
    int* rp_cop   = rp_sim + RP_OTHER;
    int* rp_bel   = rp_cop + RP_OTHER;
    int* rp_comp  = rp_bel + RP_OTHER;

    float* out_c = (float*)d_out;
    float* out_p = out_c + CSZ;
    float* out_g = out_p + PSZ;
    float* out_b = out_g + (size_t)NG * 64;

    const int BT = 256;

    // ---- fused convert (also copies group/brand f32 outputs) ----
    const long long CVT = (long long)(NC + NP + NG + NB) * 8;
    convert_all<<<cdiv(CVT, BT), BT, 0, stream>>>(
        cust_w, prod_w, group_w, brand_w, c16A, p16A, g16, b16, out_g, out_b);

    // ---- CSR build: bucket-count -> bucket-scan -> multisplit -> bucket sort ----
    Edges6 E;
    E.src[0] = (const int*)d_in[4];  E.dst[0] = (const int*)d_in[5];
    E.src[1] = (const int*)d_in[6];  E.dst[1] = (const int*)d_in[7];
    E.src[2] = (const int*)d_in[8];  E.dst[2] = (const int*)d_in[9];
    E.src[3] = (const int*)d_in[10]; E.dst[3] = (const int*)d_in[11];
    E.src[4] = (const int*)d_in[12]; E.dst[4] = (const int*)d_in[13];
    E.src[5] = (const int*)d_in[14]; E.dst[5] = (const int*)d_in[15];
    E.cum[0] = 0;
    for (int k = 0; k < 6; ++k) E.cum[k + 1] = E.cum[k] + n_edges[k];
    E.ctbase[0] = 0;
    E.ctbase[1] = RP_PURCH;
    for (int k = 2; k < 6; ++k) E.ctbase[k] = E.ctbase[k - 1] + RP_OTHER;
    E.ctbase[6] = RTOT;
    const int TOT = E.cum[6];

    hipMemsetAsync(gcount, 0, (size_t)NBKT * 4, stream);
    bcount<<<cdiv(TOT, CH), BT, 0, stream>>>(E, gcount, TOT);
    bscan<<<1, SCAN_B, 0, stream>>>(gcount, gbase, gcur, NBKT);
    msplit<<<cdiv(TOT, CH), BT, 0, stream>>>(E, gcur, stage, TOT);
    sortb<<<NBKT, 512, 0, stream>>>(gbase, stage, pm_all, rp_all, RTOT);

    // ---- 3 fused layers ----
    const long long LTHREADS = (long long)(NP + NC) * 8;
    layer_kernel<<<cdiv(LTHREADS, BT), BT, 0, stream>>>(
        rp_purch, rp_pby, rp_sim, rp_cop, rp_bel, rp_comp, pm_all,
        c16A, p16A, g16, b16, c16B, p16B, out_c, out_p, 0);
    layer_kernel<<<cdiv(LTHREADS, BT), BT, 0, stream>>>(
        rp_purch, rp_pby, rp_sim, rp_cop, rp_bel, rp_comp, pm_all,
        c16B, p16B, g16, b16, c16A, p16A, out_c, out_p, 1);
    layer_kernel<<<cdiv(LTHREADS, BT), BT, 0, stream>>>(
        rp_purch, rp_pby, rp_sim, rp_cop, rp_bel, rp_comp, pm_all,
        c16A, p16A, g16, b16, c16B, p16B, out_c, out_p, 2);
}